// Round 15
// baseline (76.951 us; speedup 1.0000x reference)
//
#include <hip/hip_runtime.h>
#include <hip/hip_bf16.h>
#include <math.h>

#define B 64
#define L 64
#define NPT 127
#define D 128
#define VOCAB 30000
#define LABELS 30
#define SPLIT 4
#define KP 132    // padded LDS row stride (floats) for K/V tiles in k2 (16B-aligned)
#define WCS 136   // wcT row stride in ushorts (272B: 16B-aligned)

typedef __attribute__((ext_vector_type(8))) short bf16x8;
typedef __attribute__((ext_vector_type(4))) float f32x4;

__device__ __forceinline__ float bfhi(unsigned int u) {
  unsigned int x = u & 0xffff0000u;
  return __builtin_bit_cast(float, x);
}
__device__ __forceinline__ float bflo(unsigned int u) {
  unsigned int x = u << 16;
  return __builtin_bit_cast(float, x);
}
__device__ __forceinline__ unsigned short f2bf(float f) {
  __hip_bfloat16 h = __float2bfloat16(f);  // RNE
  return __builtin_bit_cast(unsigned short, h);
}

// ---------------------------------------------------------------------------
// K0 (MFMA): T[v][e] = bf16( sum_d emb[v][d]*Wc[d][e] + bc[e] )
// ---------------------------------------------------------------------------
__global__ __launch_bounds__(256) void k0_embWc(const float* __restrict__ emb,
                                                const float* __restrict__ Wc,
                                                const float* __restrict__ bc,
                                                __hip_bfloat16* __restrict__ T) {
  __shared__ unsigned short wcT[D * WCS];  // Wc^T bf16: wcT[e*WCS + d], ~34KB
  const int t = threadIdx.x;
  for (int i = t; i < D * D / 4; i += 256) {
    const int d = i >> 5;            // row of Wc
    const int e0 = (i & 31) * 4;     // 4 consecutive cols (lane-fast)
    float4 wv = *(const float4*)&Wc[d * D + e0];
    wcT[(e0 + 0) * WCS + d] = f2bf(wv.x);
    wcT[(e0 + 1) * WCS + d] = f2bf(wv.y);
    wcT[(e0 + 2) * WCS + d] = f2bf(wv.z);
    wcT[(e0 + 3) * WCS + d] = f2bf(wv.w);
  }
  __syncthreads();
  const int w = t >> 6, lane = t & 63;
  const int m = lane & 15;       // A-row / B-col within tile
  const int kg = lane >> 4;      // k-group 0..3
  int arow = blockIdx.x * 64 + w * 16 + m;
  if (arow >= VOCAB) arow = VOCAB - 1;  // clamp reads; stores guarded below
  const float* ap = emb + (size_t)arow * D + kg * 8;
  bf16x8 afrag[4];
#pragma unroll
  for (int kc = 0; kc < 4; ++kc) {
    float4 lo = *(const float4*)(ap + kc * 32);
    float4 hi = *(const float4*)(ap + kc * 32 + 4);
    union { bf16x8 v; unsigned short s[8]; } u;
    u.s[0] = f2bf(lo.x); u.s[1] = f2bf(lo.y); u.s[2] = f2bf(lo.z); u.s[3] = f2bf(lo.w);
    u.s[4] = f2bf(hi.x); u.s[5] = f2bf(hi.y); u.s[6] = f2bf(hi.z); u.s[7] = f2bf(hi.w);
    afrag[kc] = u.v;
  }
  const int grow0 = blockIdx.x * 64 + w * 16 + kg * 4;
#pragma unroll
  for (int ct = 0; ct < 8; ++ct) {
    const int col = ct * 16 + m;
    f32x4 acc = {0.f, 0.f, 0.f, 0.f};
#pragma unroll
    for (int kc = 0; kc < 4; ++kc) {
      bf16x8 bfrag = *(const bf16x8*)&wcT[col * WCS + kc * 32 + kg * 8];
      acc = __builtin_amdgcn_mfma_f32_16x16x32_bf16(afrag[kc], bfrag, acc, 0, 0, 0);
    }
    const float bcv = bc[col];
#pragma unroll
    for (int r = 0; r < 4; ++r) {
      const int grow = grow0 + r;
      if (grow < VOCAB)
        T[(size_t)grow * D + col] = __float2bfloat16(acc[r] + bcv);
    }
  }
}

// ---------------------------------------------------------------------------
// KPRE: stream T sequentially to warm L2/L3 before the random gather.
// Data-dependent never-taken store keeps the loads alive.
// ---------------------------------------------------------------------------
__global__ __launch_bounds__(256) void kpre_warm(const float4* __restrict__ T4,
                                                 float* __restrict__ sink) {
  const size_t i = (size_t)blockIdx.x * 256 + threadIdx.x;
  float4 v = T4[i];
  float s = v.x + v.y + v.z + v.w;
  if (s == 1.2345678e-33f) sink[0] = s;  // never true for real data
}

// ---------------------------------------------------------------------------
// K1 (fused tree + qkv): phase 1 = one WAVE per (b,l) row. Tree processed as
// 8 independent 15-node static subtrees + 7-node top combine; scalar token
// loads. phase 2 = coalesced qkv projection (t<384).
// ---------------------------------------------------------------------------
__global__ __launch_bounds__(512, 4) void k1_tree_qkv(
    const int* __restrict__ tokens, const __hip_bfloat16* __restrict__ T,
    const float* __restrict__ Wq, const float* __restrict__ Wk,
    const float* __restrict__ Wv, float* __restrict__ qb,
    float* __restrict__ kb, float* __restrict__ vb) {
  __shared__ float sEnc[8][D];
  const int t = threadIdx.x;
  const int w = __builtin_amdgcn_readfirstlane(t >> 6);  // wave id, SGPR
  const int lane = t & 63;
  const int row = blockIdx.x * 8 + w;                    // wave-uniform
  const int* __restrict__ tokrow = tokens + (size_t)row * NPT;
  const unsigned* Tp = (const unsigned*)T;  // one u32 = dim pair; row = 64 u32
  float m0 = -1e30f, m1 = -1e30f;
  float ra0[8], ra1[8];  // 8 subtree roots (level-3 nodes 7..14)
#pragma unroll
  for (int g = 0; g < 8; ++g) {
    unsigned nl[8], np[4], nq[2], nr;
#pragma unroll
    for (int i = 0; i < 8; ++i)
      nl[i] = Tp[(size_t)tokrow[63 + 8 * g + i] * 64 + lane];
#pragma unroll
    for (int i = 0; i < 4; ++i)
      np[i] = Tp[(size_t)tokrow[31 + 4 * g + i] * 64 + lane];
#pragma unroll
    for (int i = 0; i < 2; ++i)
      nq[i] = Tp[(size_t)tokrow[15 + 2 * g + i] * 64 + lane];
    nr = Tp[(size_t)tokrow[7 + g] * 64 + lane];
    float p0[4], p1[4];
#pragma unroll
    for (int i = 0; i < 4; ++i) {
      float a0 = bflo(nl[2 * i]), a1 = bfhi(nl[2 * i]);
      float b0 = bflo(nl[2 * i + 1]), b1 = bfhi(nl[2 * i + 1]);
      m0 = fmaxf(m0, fmaxf(a0, b0));
      m1 = fmaxf(m1, fmaxf(a1, b1));
      p0[i] = bflo(np[i]) + (a0 + b0);
      p1[i] = bfhi(np[i]) + (a1 + b1);
      m0 = fmaxf(m0, p0[i]);
      m1 = fmaxf(m1, p1[i]);
    }
    float q0[2], q1[2];
#pragma unroll
    for (int i = 0; i < 2; ++i) {
      q0[i] = bflo(nq[i]) + (p0[2 * i] + p0[2 * i + 1]);
      q1[i] = bfhi(nq[i]) + (p1[2 * i] + p1[2 * i + 1]);
      m0 = fmaxf(m0, q0[i]);
      m1 = fmaxf(m1, q1[i]);
    }
    ra0[g] = bflo(nr) + (q0[0] + q0[1]);
    ra1[g] = bfhi(nr) + (q1[0] + q1[1]);
    m0 = fmaxf(m0, ra0[g]);
    m1 = fmaxf(m1, ra1[g]);
  }
  unsigned ns[4], nt0, nt1, n0;
#pragma unroll
  for (int i = 0; i < 4; ++i) ns[i] = Tp[(size_t)tokrow[3 + i] * 64 + lane];
  nt0 = Tp[(size_t)tokrow[1] * 64 + lane];
  nt1 = Tp[(size_t)tokrow[2] * 64 + lane];
  n0 = Tp[(size_t)tokrow[0] * 64 + lane];
  float s0[4], s1[4];
#pragma unroll
  for (int i = 0; i < 4; ++i) {
    s0[i] = bflo(ns[i]) + (ra0[2 * i] + ra0[2 * i + 1]);
    s1[i] = bfhi(ns[i]) + (ra1[2 * i] + ra1[2 * i + 1]);
    m0 = fmaxf(m0, s0[i]);
    m1 = fmaxf(m1, s1[i]);
  }
  float ta0 = bflo(nt0) + (s0[0] + s0[1]);
  float ta1 = bfhi(nt0) + (s1[0] + s1[1]);
  float tb0 = bflo(nt1) + (s0[2] + s0[3]);
  float tb1 = bfhi(nt1) + (s1[2] + s1[3]);
  m0 = fmaxf(m0, fmaxf(ta0, tb0));
  m1 = fmaxf(m1, fmaxf(ta1, tb1));
  float v0 = bflo(n0) + (ta0 + tb0);
  float v1 = bfhi(n0) + (ta1 + tb1);
  m0 = fmaxf(m0, v0);
  m1 = fmaxf(m1, v1);
  sEnc[w][2 * lane] = fmaxf(m0, 0.0f);
  sEnc[w][2 * lane + 1] = fmaxf(m1, 0.0f);
  __syncthreads();
  if (t < 384) {
    const int mi = t >> 7;        // 0=q, 1=k, 2=v
    const int c = t & 127;
    const float* W = mi == 0 ? Wq : (mi == 1 ? Wk : Wv);
    float* outb = mi == 0 ? qb : (mi == 1 ? kb : vb);
    float acc[8] = {};
#pragma unroll 8
    for (int k = 0; k < D; ++k) {
      float wvv = W[k * D + c];   // coalesced across 128 lanes
#pragma unroll
      for (int r = 0; r < 8; ++r) acc[r] += sEnc[r][k] * wvv;  // broadcasts
    }
    const int row0 = blockIdx.x * 8;
#pragma unroll
    for (int r = 0; r < 8; ++r)
      outb[(size_t)(row0 + r) * D + c] = acc[r];
  }
}

// ---------------------------------------------------------------------------
// K2 (fused attn + Wo-proj + partial pool): one (batch, split of 16 q-rows)
// per block. Attention rows -> sOr LDS; proj with coalesced Wo loads;
// block writes 16-row pooled max to pool[b*SPLIT+sp].
// ---------------------------------------------------------------------------
__global__ __launch_bounds__(512) void k2_attn_proj(
    const float* __restrict__ qb, const float* __restrict__ kb,
    const float* __restrict__ vb, const int* __restrict__ mask,
    const float* __restrict__ Wo, float* __restrict__ pool) {
  __shared__ float sK[L * KP];      // 33.8 KB
  __shared__ float sV[L * KP];      // 33.8 KB
  __shared__ float sQ[8][D];        // 4 KB
  __shared__ float sOr[16][D];      // 8 KB
  __shared__ float pmax[4][D];      // 2 KB
  const int t = threadIdx.x;
  const int w = t >> 6, lane = t & 63;
  const int b = blockIdx.x / SPLIT;
  const int sp = blockIdx.x % SPLIT;
  for (int i = t * 4; i < L * D; i += 512 * 4) {
    int r = i >> 7, c = i & 127;
    float4 kv = *(const float4*)&kb[(size_t)(b * L + r) * D + c];
    float4 vv = *(const float4*)&vb[(size_t)(b * L + r) * D + c];
    *(float4*)&sK[r * KP + c] = kv;
    *(float4*)&sV[r * KP + c] = vv;
  }
  __syncthreads();
#pragma unroll
  for (int it = 0; it < 2; ++it) {
    const int r = sp * 16 + w * 2 + it;
    float2 qv = *(const float2*)&qb[(size_t)(b * L + r) * D + lane * 2];
    sQ[w][lane * 2] = qv.x;
    sQ[w][lane * 2 + 1] = qv.y;
    float sc = 0.f;
    const float4* kr = (const float4*)&sK[lane * KP];
    const float4* qr = (const float4*)&sQ[w][0];
#pragma unroll 8
    for (int k4 = 0; k4 < 32; ++k4) {
      float4 kv = kr[k4];
      float4 q4 = qr[k4];
      sc += q4.x * kv.x + q4.y * kv.y + q4.z * kv.z + q4.w * kv.w;
    }
    sc *= 0.08838834764831845f;
    if (mask[((size_t)b * L + r) * L + lane] <= 0) sc = -1e9f;
    float mx = sc;
#pragma unroll
    for (int off = 32; off >= 1; off >>= 1) mx = fmaxf(mx, __shfl_xor(mx, off));
    float ex = __expf(sc - mx);
    float sm = ex;
#pragma unroll
    for (int off = 32; off >= 1; off >>= 1) sm += __shfl_xor(sm, off);
    float a = ex / sm;
    float o0 = 0.f, o1 = 0.f;
#pragma unroll
    for (int j = 0; j < L; ++j) {
      float aj = __shfl(a, j);
      o0 += aj * sV[j * KP + lane];
      o1 += aj * sV[j * KP + lane + 64];
    }
    sOr[w * 2 + it][lane] = o0;
    sOr[w * 2 + it][lane + 64] = o1;
  }
  __syncthreads();
  // Wo projection: thread -> (col c, row group rg of 4 rows); coalesced Wo.
  {
    const int c = t & 127;
    const int rg = t >> 7;  // 0..3
    float acc[4] = {};
#pragma unroll 4
    for (int k = 0; k < D; ++k) {
      float wv = Wo[k * D + c];   // coalesced across 128 lanes
#pragma unroll
      for (int r = 0; r < 4; ++r) acc[r] += sOr[rg * 4 + r][k] * wv;
    }
    float pm = fmaxf(fmaxf(acc[0], acc[1]), fmaxf(acc[2], acc[3]));
    pmax[rg][c] = pm;
  }
  __syncthreads();
  if (t < 128) {
    float pv = fmaxf(fmaxf(pmax[0][t], pmax[1][t]), fmaxf(pmax[2][t], pmax[3][t]));
    pool[(size_t)blockIdx.x * D + t] = pv;
  }
}

// ---------------------------------------------------------------------------
// K3: final pooled max over splits + logits
// ---------------------------------------------------------------------------
__global__ __launch_bounds__(128) void k3_logits(const float* __restrict__ pool,
                                                 const float* __restrict__ Wl,
                                                 const float* __restrict__ bl,
                                                 float* __restrict__ out) {
  __shared__ float sP[D];
  const int b = blockIdx.x, t = threadIdx.x;
  float pv = pool[((size_t)b * SPLIT) * D + t];
#pragma unroll
  for (int i = 1; i < SPLIT; ++i)
    pv = fmaxf(pv, pool[((size_t)b * SPLIT + i) * D + t]);
  sP[t] = pv;
  __syncthreads();
  if (t < LABELS) {
    float a = bl[t];
#pragma unroll 4
    for (int d = 0; d < D; ++d) a += sP[d] * Wl[d * LABELS + t];
    out[b * LABELS + t] = a;
  }
}

extern "C" void kernel_launch(void* const* d_in, const int* in_sizes, int n_in,
                              void* d_out, int out_size, void* d_ws, size_t ws_size,
                              hipStream_t stream) {
  const int* tokens = (const int*)d_in[0];
  const int* mask = (const int*)d_in[1];
  const float* emb = (const float*)d_in[2];
  const float* Wc = (const float*)d_in[3];
  const float* bc = (const float*)d_in[4];
  const float* Wq = (const float*)d_in[5];
  const float* Wk = (const float*)d_in[6];
  const float* Wv = (const float*)d_in[7];
  const float* Wo = (const float*)d_in[8];
  const float* Wl = (const float*)d_in[9];
  const float* bl = (const float*)d_in[10];
  float* out = (float*)d_out;

  __hip_bfloat16* T = (__hip_bfloat16*)d_ws;        // VOCAB*D bf16 = 7.68 MB
  float* qb = (float*)(T + (size_t)VOCAB * D);      // B*L*D f32 each
  float* kb = qb + (size_t)B * L * D;
  float* vb = kb + (size_t)B * L * D;
  float* pool = vb + (size_t)B * L * D;             // B*SPLIT*D
  float* sink = pool + (size_t)B * SPLIT * D;       // 1 float scratch

  hipLaunchKernelGGL(k0_embWc, dim3((VOCAB + 63) / 64), dim3(256), 0, stream,
                     emb, Wc, bc, T);
  // warm T (VOCAB*D*2 bytes = 7.68 MB = 480K float4 reads) into L2/L3
  hipLaunchKernelGGL(kpre_warm, dim3(VOCAB * D * 2 / 16 / 256), dim3(256), 0,
                     stream, (const float4*)T, sink);
  hipLaunchKernelGGL(k1_tree_qkv, dim3(B * L / 8), dim3(512), 0, stream,
                     tokens, T, Wq, Wk, Wv, qb, kb, vb);
  hipLaunchKernelGGL(k2_attn_proj, dim3(B * SPLIT), dim3(512), 0, stream,
                     qb, kb, vb, mask, Wo, pool);
  hipLaunchKernelGGL(k3_logits, dim3(B), dim3(128), 0, stream,
                     pool, Wl, bl, out);
}

// Round 16
// 64.577 us; speedup vs baseline: 1.1916x; 1.1916x over previous
//
#include <hip/hip_runtime.h>
#include <hip/hip_bf16.h>
#include <math.h>

#define B 64
#define L 64
#define NPT 127
#define D 128
#define VOCAB 30000
#define LABELS 30
#define SPLIT 4
#define WCS 136   // bf16 LDS row stride in ushorts (272B: 16B-aligned)
#define VTS 72    // V^T row stride in ushorts (144B: 16B-aligned)

typedef __attribute__((ext_vector_type(8))) short bf16x8;
typedef __attribute__((ext_vector_type(4))) float f32x4;

__device__ __forceinline__ float bfhi(unsigned int u) {
  unsigned int x = u & 0xffff0000u;
  return __builtin_bit_cast(float, x);
}
__device__ __forceinline__ float bflo(unsigned int u) {
  unsigned int x = u << 16;
  return __builtin_bit_cast(float, x);
}
__device__ __forceinline__ unsigned short f2bf(float f) {
  __hip_bfloat16 h = __float2bfloat16(f);  // RNE
  return __builtin_bit_cast(unsigned short, h);
}

// ---------------------------------------------------------------------------
// K0 (MFMA): T[v][e] = bf16( sum_d emb[v][d]*Wc[d][e] + bc[e] )
// ---------------------------------------------------------------------------
__global__ __launch_bounds__(256) void k0_embWc(const float* __restrict__ emb,
                                                const float* __restrict__ Wc,
                                                const float* __restrict__ bc,
                                                __hip_bfloat16* __restrict__ T) {
  __shared__ unsigned short wcT[D * WCS];  // Wc^T bf16: wcT[e*WCS + d], ~34KB
  const int t = threadIdx.x;
  for (int i = t; i < D * D / 4; i += 256) {
    const int d = i >> 5;            // row of Wc
    const int e0 = (i & 31) * 4;     // 4 consecutive cols (lane-fast)
    float4 wv = *(const float4*)&Wc[d * D + e0];
    wcT[(e0 + 0) * WCS + d] = f2bf(wv.x);
    wcT[(e0 + 1) * WCS + d] = f2bf(wv.y);
    wcT[(e0 + 2) * WCS + d] = f2bf(wv.z);
    wcT[(e0 + 3) * WCS + d] = f2bf(wv.w);
  }
  __syncthreads();
  const int w = t >> 6, lane = t & 63;
  const int m = lane & 15;       // A-row / B-col within tile
  const int kg = lane >> 4;      // k-group 0..3
  int arow = blockIdx.x * 64 + w * 16 + m;
  if (arow >= VOCAB) arow = VOCAB - 1;  // clamp reads; stores guarded below
  const float* ap = emb + (size_t)arow * D + kg * 8;
  bf16x8 afrag[4];
#pragma unroll
  for (int kc = 0; kc < 4; ++kc) {
    float4 lo = *(const float4*)(ap + kc * 32);
    float4 hi = *(const float4*)(ap + kc * 32 + 4);
    union { bf16x8 v; unsigned short s[8]; } u;
    u.s[0] = f2bf(lo.x); u.s[1] = f2bf(lo.y); u.s[2] = f2bf(lo.z); u.s[3] = f2bf(lo.w);
    u.s[4] = f2bf(hi.x); u.s[5] = f2bf(hi.y); u.s[6] = f2bf(hi.z); u.s[7] = f2bf(hi.w);
    afrag[kc] = u.v;
  }
  const int grow0 = blockIdx.x * 64 + w * 16 + kg * 4;
#pragma unroll
  for (int ct = 0; ct < 8; ++ct) {
    const int col = ct * 16 + m;
    f32x4 acc = {0.f, 0.f, 0.f, 0.f};
#pragma unroll
    for (int kc = 0; kc < 4; ++kc) {
      bf16x8 bfrag = *(const bf16x8*)&wcT[col * WCS + kc * 32 + kg * 8];
      acc = __builtin_amdgcn_mfma_f32_16x16x32_bf16(afrag[kc], bfrag, acc, 0, 0, 0);
    }
    const float bcv = bc[col];
#pragma unroll
    for (int r = 0; r < 4; ++r) {
      const int grow = grow0 + r;
      if (grow < VOCAB)
        T[(size_t)grow * D + col] = __float2bfloat16(acc[r] + bcv);
    }
  }
}

// ---------------------------------------------------------------------------
// K1 (fused tree + qkv): phase 1 = one WAVE per (b,l) row, 8 static subtrees,
// scalar token loads. phase 2 = coalesced qkv projection (t<384).
// ---------------------------------------------------------------------------
__global__ __launch_bounds__(512, 4) void k1_tree_qkv(
    const int* __restrict__ tokens, const __hip_bfloat16* __restrict__ T,
    const float* __restrict__ Wq, const float* __restrict__ Wk,
    const float* __restrict__ Wv, float* __restrict__ qb,
    float* __restrict__ kb, float* __restrict__ vb) {
  __shared__ float sEnc[8][D];
  const int t = threadIdx.x;
  const int w = __builtin_amdgcn_readfirstlane(t >> 6);  // wave id, SGPR
  const int lane = t & 63;
  const int row = blockIdx.x * 8 + w;                    // wave-uniform
  const int* __restrict__ tokrow = tokens + (size_t)row * NPT;
  const unsigned* Tp = (const unsigned*)T;  // one u32 = dim pair; row = 64 u32
  float m0 = -1e30f, m1 = -1e30f;
  float ra0[8], ra1[8];
#pragma unroll
  for (int g = 0; g < 8; ++g) {
    unsigned nl[8], np[4], nq[2], nr;
#pragma unroll
    for (int i = 0; i < 8; ++i)
      nl[i] = Tp[(size_t)tokrow[63 + 8 * g + i] * 64 + lane];
#pragma unroll
    for (int i = 0; i < 4; ++i)
      np[i] = Tp[(size_t)tokrow[31 + 4 * g + i] * 64 + lane];
#pragma unroll
    for (int i = 0; i < 2; ++i)
      nq[i] = Tp[(size_t)tokrow[15 + 2 * g + i] * 64 + lane];
    nr = Tp[(size_t)tokrow[7 + g] * 64 + lane];
    float p0[4], p1[4];
#pragma unroll
    for (int i = 0; i < 4; ++i) {
      float a0 = bflo(nl[2 * i]), a1 = bfhi(nl[2 * i]);
      float b0 = bflo(nl[2 * i + 1]), b1 = bfhi(nl[2 * i + 1]);
      m0 = fmaxf(m0, fmaxf(a0, b0));
      m1 = fmaxf(m1, fmaxf(a1, b1));
      p0[i] = bflo(np[i]) + (a0 + b0);
      p1[i] = bfhi(np[i]) + (a1 + b1);
      m0 = fmaxf(m0, p0[i]);
      m1 = fmaxf(m1, p1[i]);
    }
    float q0[2], q1[2];
#pragma unroll
    for (int i = 0; i < 2; ++i) {
      q0[i] = bflo(nq[i]) + (p0[2 * i] + p0[2 * i + 1]);
      q1[i] = bfhi(nq[i]) + (p1[2 * i] + p1[2 * i + 1]);
      m0 = fmaxf(m0, q0[i]);
      m1 = fmaxf(m1, q1[i]);
    }
    ra0[g] = bflo(nr) + (q0[0] + q0[1]);
    ra1[g] = bfhi(nr) + (q1[0] + q1[1]);
    m0 = fmaxf(m0, ra0[g]);
    m1 = fmaxf(m1, ra1[g]);
  }
  unsigned ns[4], nt0, nt1, n0;
#pragma unroll
  for (int i = 0; i < 4; ++i) ns[i] = Tp[(size_t)tokrow[3 + i] * 64 + lane];
  nt0 = Tp[(size_t)tokrow[1] * 64 + lane];
  nt1 = Tp[(size_t)tokrow[2] * 64 + lane];
  n0 = Tp[(size_t)tokrow[0] * 64 + lane];
  float s0[4], s1[4];
#pragma unroll
  for (int i = 0; i < 4; ++i) {
    s0[i] = bflo(ns[i]) + (ra0[2 * i] + ra0[2 * i + 1]);
    s1[i] = bfhi(ns[i]) + (ra1[2 * i] + ra1[2 * i + 1]);
    m0 = fmaxf(m0, s0[i]);
    m1 = fmaxf(m1, s1[i]);
  }
  float ta0 = bflo(nt0) + (s0[0] + s0[1]);
  float ta1 = bfhi(nt0) + (s1[0] + s1[1]);
  float tb0 = bflo(nt1) + (s0[2] + s0[3]);
  float tb1 = bfhi(nt1) + (s1[2] + s1[3]);
  m0 = fmaxf(m0, fmaxf(ta0, tb0));
  m1 = fmaxf(m1, fmaxf(ta1, tb1));
  float v0 = bflo(n0) + (ta0 + tb0);
  float v1 = bfhi(n0) + (ta1 + tb1);
  m0 = fmaxf(m0, v0);
  m1 = fmaxf(m1, v1);
  sEnc[w][2 * lane] = fmaxf(m0, 0.0f);
  sEnc[w][2 * lane + 1] = fmaxf(m1, 0.0f);
  __syncthreads();
  if (t < 384) {
    const int mi = t >> 7;        // 0=q, 1=k, 2=v
    const int c = t & 127;
    const float* W = mi == 0 ? Wq : (mi == 1 ? Wk : Wv);
    float* outb = mi == 0 ? qb : (mi == 1 ? kb : vb);
    float acc[8] = {};
#pragma unroll 8
    for (int k = 0; k < D; ++k) {
      float wvv = W[k * D + c];   // coalesced across 128 lanes
#pragma unroll
      for (int r = 0; r < 8; ++r) acc[r] += sEnc[r][k] * wvv;  // broadcasts
    }
    const int row0 = blockIdx.x * 8;
#pragma unroll
    for (int r = 0; r < 8; ++r)
      outb[(size_t)(row0 + r) * D + c] = acc[r];
  }
}

// ---------------------------------------------------------------------------
// K2 (MFMA attn + Wo-proj + partial pool): one (batch, split of 16 q-rows)
// per block, 512 threads = 8 waves.
//  S = Q·K^T  : waves 0-3, one 16x16 key-tile each, 4 k-chunks (D=128)
//  softmax    : 512 thr = 16 rows x 32 (2 keys each), 32-lane shuffle reduce
//  O = P·V    : 8 waves, one 16x16 dim-tile each, V^T staged (K=64)
//  OWo        : 8 waves, one 16x16 out-tile each, Wo^T staged bf16 (K=128),
//               pooled max in-register -> pool[b*SPLIT+sp]
// MFMA layouts identical to k0 (proven): A row=lane&15,k=(lane>>4)*8+j;
// B col=lane&15; C/D col=lane&15,row=(lane>>4)*4+reg.
// ---------------------------------------------------------------------------
__global__ __launch_bounds__(512) void k2_attn_proj(
    const float* __restrict__ qb, const float* __restrict__ kb,
    const float* __restrict__ vb, const int* __restrict__ mask,
    const float* __restrict__ Wo, float* __restrict__ pool) {
  __shared__ unsigned short sK[L * WCS];    // K bf16 [64][136]   17.4 KB
  __shared__ unsigned short sVt[D * VTS];   // V^T bf16 [128][72] 18.4 KB
  __shared__ unsigned short woT[D * WCS];   // Wo^T bf16 [128][136] 34.8 KB
  __shared__ float sS[16 * 68];             // scores f32          4.3 KB
  __shared__ unsigned short sP[16 * VTS];   // P bf16 [16][72]     2.3 KB
  __shared__ unsigned short sO[16 * WCS];   // O bf16 [16][136]    4.3 KB
  __shared__ float pmaxArr[D];              //                     0.5 KB
  const int t = threadIdx.x;
  const int wv_ = t >> 6, lane = t & 63;
  const int m = lane & 15;
  const int kg = lane >> 4;
  const int b = blockIdx.x / SPLIT;
  const int sp = blockIdx.x % SPLIT;
  // ---- stage K (bf16) and V^T (bf16) ----
  for (int i = t * 4; i < L * D; i += 512 * 4) {
    const int r = i >> 7, c = i & 127;
    float4 kv = *(const float4*)&kb[(size_t)(b * L + r) * D + c];
    ushort4 k4;
    k4.x = f2bf(kv.x); k4.y = f2bf(kv.y); k4.z = f2bf(kv.z); k4.w = f2bf(kv.w);
    *(ushort4*)&sK[r * WCS + c] = k4;
    float4 vv = *(const float4*)&vb[(size_t)(b * L + r) * D + c];
    sVt[(c + 0) * VTS + r] = f2bf(vv.x);
    sVt[(c + 1) * VTS + r] = f2bf(vv.y);
    sVt[(c + 2) * VTS + r] = f2bf(vv.z);
    sVt[(c + 3) * VTS + r] = f2bf(vv.w);
  }
  // ---- stage Wo^T (bf16) ----
  for (int i = t; i < D * D / 4; i += 512) {
    const int d = i >> 5;
    const int e0 = (i & 31) * 4;
    float4 wv = *(const float4*)&Wo[d * D + e0];
    woT[(e0 + 0) * WCS + d] = f2bf(wv.x);
    woT[(e0 + 1) * WCS + d] = f2bf(wv.y);
    woT[(e0 + 2) * WCS + d] = f2bf(wv.z);
    woT[(e0 + 3) * WCS + d] = f2bf(wv.w);
  }
  // ---- Q fragments (waves 0-3; q-row = m, global reads) ----
  bf16x8 qfrag[4];
  if (wv_ < 4) {
    const float* qp = qb + (size_t)(b * L + sp * 16 + m) * D + kg * 8;
#pragma unroll
    for (int kc = 0; kc < 4; ++kc) {
      float4 lo = *(const float4*)(qp + kc * 32);
      float4 hi = *(const float4*)(qp + kc * 32 + 4);
      union { bf16x8 v; unsigned short s[8]; } u;
      u.s[0] = f2bf(lo.x); u.s[1] = f2bf(lo.y); u.s[2] = f2bf(lo.z); u.s[3] = f2bf(lo.w);
      u.s[4] = f2bf(hi.x); u.s[5] = f2bf(hi.y); u.s[6] = f2bf(hi.z); u.s[7] = f2bf(hi.w);
      qfrag[kc] = u.v;
    }
  }
  __syncthreads();
  // ---- S = Q @ K^T (waves 0-3; key-tile = wv_) ----
  if (wv_ < 4) {
    f32x4 acc = {0.f, 0.f, 0.f, 0.f};
#pragma unroll
    for (int kc = 0; kc < 4; ++kc) {
      bf16x8 bfrag = *(const bf16x8*)&sK[(wv_ * 16 + m) * WCS + kc * 32 + kg * 8];
      acc = __builtin_amdgcn_mfma_f32_16x16x32_bf16(qfrag[kc], bfrag, acc, 0, 0, 0);
    }
#pragma unroll
    for (int r = 0; r < 4; ++r)
      sS[(kg * 4 + r) * 68 + wv_ * 16 + m] = acc[r];
  }
  __syncthreads();
  // ---- softmax: 16 rows x 32 threads (2 keys each) ----
  {
    const int row = t >> 5;
    const int k2i = (t & 31) * 2;
    float s0 = sS[row * 68 + k2i] * 0.08838834764831845f;
    float s1 = sS[row * 68 + k2i + 1] * 0.08838834764831845f;
    const int* mp = &mask[((size_t)(b * L + sp * 16 + row)) * L + k2i];
    if (mp[0] <= 0) s0 = -1e9f;
    if (mp[1] <= 0) s1 = -1e9f;
    float mx = fmaxf(s0, s1);
#pragma unroll
    for (int off = 16; off >= 1; off >>= 1) mx = fmaxf(mx, __shfl_xor(mx, off));
    float e0 = __expf(s0 - mx), e1 = __expf(s1 - mx);
    float sm = e0 + e1;
#pragma unroll
    for (int off = 16; off >= 1; off >>= 1) sm += __shfl_xor(sm, off);
    float inv = 1.0f / sm;
    unsigned short p0 = f2bf(e0 * inv), p1 = f2bf(e1 * inv);
    *(unsigned*)&sP[row * VTS + k2i] =
        (unsigned)p0 | ((unsigned)p1 << 16);
  }
  __syncthreads();
  // ---- O = P @ V (8 waves; dim-tile = wv_) ----
  {
    f32x4 acc = {0.f, 0.f, 0.f, 0.f};
#pragma unroll
    for (int kc = 0; kc < 2; ++kc) {
      bf16x8 pa = *(const bf16x8*)&sP[m * VTS + kc * 32 + kg * 8];
      bf16x8 vf = *(const bf16x8*)&sVt[(wv_ * 16 + m) * VTS + kc * 32 + kg * 8];
      acc = __builtin_amdgcn_mfma_f32_16x16x32_bf16(pa, vf, acc, 0, 0, 0);
    }
#pragma unroll
    for (int r = 0; r < 4; ++r)
      sO[(kg * 4 + r) * WCS + wv_ * 16 + m] = f2bf(acc[r]);
  }
  __syncthreads();
  // ---- OWo + pooled max (8 waves; out-tile = wv_) ----
  {
    f32x4 acc = {0.f, 0.f, 0.f, 0.f};
#pragma unroll
    for (int kc = 0; kc < 4; ++kc) {
      bf16x8 oa = *(const bf16x8*)&sO[m * WCS + kc * 32 + kg * 8];
      bf16x8 wb = *(const bf16x8*)&woT[(wv_ * 16 + m) * WCS + kc * 32 + kg * 8];
      acc = __builtin_amdgcn_mfma_f32_16x16x32_bf16(oa, wb, acc, 0, 0, 0);
    }
    float v = fmaxf(fmaxf(acc[0], acc[1]), fmaxf(acc[2], acc[3]));
    v = fmaxf(v, __shfl_xor(v, 16));
    v = fmaxf(v, __shfl_xor(v, 32));
    if (kg == 0) pmaxArr[wv_ * 16 + m] = v;
  }
  __syncthreads();
  if (t < D) pool[(size_t)blockIdx.x * D + t] = pmaxArr[t];
}

// ---------------------------------------------------------------------------
// K3: final pooled max over splits + logits
// ---------------------------------------------------------------------------
__global__ __launch_bounds__(128) void k3_logits(const float* __restrict__ pool,
                                                 const float* __restrict__ Wl,
                                                 const float* __restrict__ bl,
                                                 float* __restrict__ out) {
  __shared__ float sP2[D];
  const int b = blockIdx.x, t = threadIdx.x;
  float pv = pool[((size_t)b * SPLIT) * D + t];
#pragma unroll
  for (int i = 1; i < SPLIT; ++i)
    pv = fmaxf(pv, pool[((size_t)b * SPLIT + i) * D + t]);
  sP2[t] = pv;
  __syncthreads();
  if (t < LABELS) {
    float a = bl[t];
#pragma unroll 4
    for (int d = 0; d < D; ++d) a += sP2[d] * Wl[d * LABELS + t];
    out[b * LABELS + t] = a;
  }
}

extern "C" void kernel_launch(void* const* d_in, const int* in_sizes, int n_in,
                              void* d_out, int out_size, void* d_ws, size_t ws_size,
                              hipStream_t stream) {
  const int* tokens = (const int*)d_in[0];
  const int* mask = (const int*)d_in[1];
  const float* emb = (const float*)d_in[2];
  const float* Wc = (const float*)d_in[3];
  const float* bc = (const float*)d_in[4];
  const float* Wq = (const float*)d_in[5];
  const float* Wk = (const float*)d_in[6];
  const float* Wv = (const float*)d_in[7];
  const float* Wo = (const float*)d_in[8];
  const float* Wl = (const float*)d_in[9];
  const float* bl = (const float*)d_in[10];
  float* out = (float*)d_out;

  __hip_bfloat16* T = (__hip_bfloat16*)d_ws;        // VOCAB*D bf16 = 7.68 MB
  float* qb = (float*)(T + (size_t)VOCAB * D);      // B*L*D f32 each
  float* kb = qb + (size_t)B * L * D;
  float* vb = kb + (size_t)B * L * D;
  float* pool = vb + (size_t)B * L * D;             // B*SPLIT*D

  hipLaunchKernelGGL(k0_embWc, dim3((VOCAB + 63) / 64), dim3(256), 0, stream,
                     emb, Wc, bc, T);
  hipLaunchKernelGGL(k1_tree_qkv, dim3(B * L / 8), dim3(512), 0, stream,
                     tokens, T, Wq, Wk, Wv, qb, kb, vb);
  hipLaunchKernelGGL(k2_attn_proj, dim3(B * SPLIT), dim3(512), 0, stream,
                     qb, kb, vb, mask, Wo, pool);
  hipLaunchKernelGGL(k3_logits, dim3(B), dim3(128), 0, stream,
                     pool, Wl, bl, out);
}

// Round 17
// 63.851 us; speedup vs baseline: 1.2052x; 1.0114x over previous
//
#include <hip/hip_runtime.h>
#include <hip/hip_bf16.h>
#include <math.h>

#define B 64
#define L 64
#define NPT 127
#define D 128
#define VOCAB 30000
#define LABELS 30
#define SPLIT 4
#define WCS 136   // bf16 LDS row stride in ushorts (272B: 16B-aligned)
#define VTS 72    // V^T row stride in ushorts (144B: 16B-aligned)

typedef __attribute__((ext_vector_type(8))) short bf16x8;
typedef __attribute__((ext_vector_type(4))) float f32x4;

__device__ __forceinline__ float bfhi(unsigned int u) {
  unsigned int x = u & 0xffff0000u;
  return __builtin_bit_cast(float, x);
}
__device__ __forceinline__ float bflo(unsigned int u) {
  unsigned int x = u << 16;
  return __builtin_bit_cast(float, x);
}
__device__ __forceinline__ unsigned short f2bf(float f) {
  __hip_bfloat16 h = __float2bfloat16(f);  // RNE
  return __builtin_bit_cast(unsigned short, h);
}

// ---------------------------------------------------------------------------
// K0 (MFMA): T[v][e] = bf16( sum_d emb[v][d]*Wc[d][e] + bc[e] )
// ---------------------------------------------------------------------------
__global__ __launch_bounds__(256) void k0_embWc(const float* __restrict__ emb,
                                                const float* __restrict__ Wc,
                                                const float* __restrict__ bc,
                                                __hip_bfloat16* __restrict__ T) {
  __shared__ unsigned short wcT[D * WCS];  // Wc^T bf16: wcT[e*WCS + d], ~34KB
  const int t = threadIdx.x;
  for (int i = t; i < D * D / 4; i += 256) {
    const int d = i >> 5;            // row of Wc
    const int e0 = (i & 31) * 4;     // 4 consecutive cols (lane-fast)
    float4 wv = *(const float4*)&Wc[d * D + e0];
    wcT[(e0 + 0) * WCS + d] = f2bf(wv.x);
    wcT[(e0 + 1) * WCS + d] = f2bf(wv.y);
    wcT[(e0 + 2) * WCS + d] = f2bf(wv.z);
    wcT[(e0 + 3) * WCS + d] = f2bf(wv.w);
  }
  __syncthreads();
  const int w = t >> 6, lane = t & 63;
  const int m = lane & 15;       // A-row / B-col within tile
  const int kg = lane >> 4;      // k-group 0..3
  int arow = blockIdx.x * 64 + w * 16 + m;
  if (arow >= VOCAB) arow = VOCAB - 1;  // clamp reads; stores guarded below
  const float* ap = emb + (size_t)arow * D + kg * 8;
  bf16x8 afrag[4];
#pragma unroll
  for (int kc = 0; kc < 4; ++kc) {
    float4 lo = *(const float4*)(ap + kc * 32);
    float4 hi = *(const float4*)(ap + kc * 32 + 4);
    union { bf16x8 v; unsigned short s[8]; } u;
    u.s[0] = f2bf(lo.x); u.s[1] = f2bf(lo.y); u.s[2] = f2bf(lo.z); u.s[3] = f2bf(lo.w);
    u.s[4] = f2bf(hi.x); u.s[5] = f2bf(hi.y); u.s[6] = f2bf(hi.z); u.s[7] = f2bf(hi.w);
    afrag[kc] = u.v;
  }
  const int grow0 = blockIdx.x * 64 + w * 16 + kg * 4;
#pragma unroll
  for (int ct = 0; ct < 8; ++ct) {
    const int col = ct * 16 + m;
    f32x4 acc = {0.f, 0.f, 0.f, 0.f};
#pragma unroll
    for (int kc = 0; kc < 4; ++kc) {
      bf16x8 bfrag = *(const bf16x8*)&wcT[col * WCS + kc * 32 + kg * 8];
      acc = __builtin_amdgcn_mfma_f32_16x16x32_bf16(afrag[kc], bfrag, acc, 0, 0, 0);
    }
    const float bcv = bc[col];
#pragma unroll
    for (int r = 0; r < 4; ++r) {
      const int grow = grow0 + r;
      if (grow < VOCAB)
        T[(size_t)grow * D + col] = __float2bfloat16(acc[r] + bcv);
    }
  }
}

// ---------------------------------------------------------------------------
// K1 (fused tree + qkv): phase 1 = one WAVE per (b,l) row, 8 static subtrees,
// scalar token loads. phase 2 = coalesced qkv projection (t<384), outputs
// stored as bf16 (same RNE rounding k2 formerly applied -> identical numerics).
// ---------------------------------------------------------------------------
__global__ __launch_bounds__(512, 4) void k1_tree_qkv(
    const int* __restrict__ tokens, const __hip_bfloat16* __restrict__ T,
    const float* __restrict__ Wq, const float* __restrict__ Wk,
    const float* __restrict__ Wv, unsigned short* __restrict__ qb,
    unsigned short* __restrict__ kb, unsigned short* __restrict__ vb) {
  __shared__ float sEnc[8][D];
  const int t = threadIdx.x;
  const int w = __builtin_amdgcn_readfirstlane(t >> 6);  // wave id, SGPR
  const int lane = t & 63;
  const int row = blockIdx.x * 8 + w;                    // wave-uniform
  const int* __restrict__ tokrow = tokens + (size_t)row * NPT;
  const unsigned* Tp = (const unsigned*)T;  // one u32 = dim pair; row = 64 u32
  float m0 = -1e30f, m1 = -1e30f;
  float ra0[8], ra1[8];
#pragma unroll
  for (int g = 0; g < 8; ++g) {
    unsigned nl[8], np[4], nq[2], nr;
#pragma unroll
    for (int i = 0; i < 8; ++i)
      nl[i] = Tp[(size_t)tokrow[63 + 8 * g + i] * 64 + lane];
#pragma unroll
    for (int i = 0; i < 4; ++i)
      np[i] = Tp[(size_t)tokrow[31 + 4 * g + i] * 64 + lane];
#pragma unroll
    for (int i = 0; i < 2; ++i)
      nq[i] = Tp[(size_t)tokrow[15 + 2 * g + i] * 64 + lane];
    nr = Tp[(size_t)tokrow[7 + g] * 64 + lane];
    float p0[4], p1[4];
#pragma unroll
    for (int i = 0; i < 4; ++i) {
      float a0 = bflo(nl[2 * i]), a1 = bfhi(nl[2 * i]);
      float b0 = bflo(nl[2 * i + 1]), b1 = bfhi(nl[2 * i + 1]);
      m0 = fmaxf(m0, fmaxf(a0, b0));
      m1 = fmaxf(m1, fmaxf(a1, b1));
      p0[i] = bflo(np[i]) + (a0 + b0);
      p1[i] = bfhi(np[i]) + (a1 + b1);
      m0 = fmaxf(m0, p0[i]);
      m1 = fmaxf(m1, p1[i]);
    }
    float q0[2], q1[2];
#pragma unroll
    for (int i = 0; i < 2; ++i) {
      q0[i] = bflo(nq[i]) + (p0[2 * i] + p0[2 * i + 1]);
      q1[i] = bfhi(nq[i]) + (p1[2 * i] + p1[2 * i + 1]);
      m0 = fmaxf(m0, q0[i]);
      m1 = fmaxf(m1, q1[i]);
    }
    ra0[g] = bflo(nr) + (q0[0] + q0[1]);
    ra1[g] = bfhi(nr) + (q1[0] + q1[1]);
    m0 = fmaxf(m0, ra0[g]);
    m1 = fmaxf(m1, ra1[g]);
  }
  unsigned ns[4], nt0, nt1, n0;
#pragma unroll
  for (int i = 0; i < 4; ++i) ns[i] = Tp[(size_t)tokrow[3 + i] * 64 + lane];
  nt0 = Tp[(size_t)tokrow[1] * 64 + lane];
  nt1 = Tp[(size_t)tokrow[2] * 64 + lane];
  n0 = Tp[(size_t)tokrow[0] * 64 + lane];
  float s0[4], s1[4];
#pragma unroll
  for (int i = 0; i < 4; ++i) {
    s0[i] = bflo(ns[i]) + (ra0[2 * i] + ra0[2 * i + 1]);
    s1[i] = bfhi(ns[i]) + (ra1[2 * i] + ra1[2 * i + 1]);
    m0 = fmaxf(m0, s0[i]);
    m1 = fmaxf(m1, s1[i]);
  }
  float ta0 = bflo(nt0) + (s0[0] + s0[1]);
  float ta1 = bfhi(nt0) + (s1[0] + s1[1]);
  float tb0 = bflo(nt1) + (s0[2] + s0[3]);
  float tb1 = bfhi(nt1) + (s1[2] + s1[3]);
  m0 = fmaxf(m0, fmaxf(ta0, tb0));
  m1 = fmaxf(m1, fmaxf(ta1, tb1));
  float v0 = bflo(n0) + (ta0 + tb0);
  float v1 = bfhi(n0) + (ta1 + tb1);
  m0 = fmaxf(m0, v0);
  m1 = fmaxf(m1, v1);
  sEnc[w][2 * lane] = fmaxf(m0, 0.0f);
  sEnc[w][2 * lane + 1] = fmaxf(m1, 0.0f);
  __syncthreads();
  if (t < 384) {
    const int mi = t >> 7;        // 0=q, 1=k, 2=v
    const int c = t & 127;
    const float* W = mi == 0 ? Wq : (mi == 1 ? Wk : Wv);
    unsigned short* outb = mi == 0 ? qb : (mi == 1 ? kb : vb);
    float acc[8] = {};
#pragma unroll 8
    for (int k = 0; k < D; ++k) {
      float wvv = W[k * D + c];   // coalesced across 128 lanes
#pragma unroll
      for (int r = 0; r < 8; ++r) acc[r] += sEnc[r][k] * wvv;  // broadcasts
    }
    const int row0 = blockIdx.x * 8;
#pragma unroll
    for (int r = 0; r < 8; ++r)
      outb[(size_t)(row0 + r) * D + c] = f2bf(acc[r]);
  }
}

// ---------------------------------------------------------------------------
// K2 (MFMA attn + Wo-proj + partial pool): one (batch, split of 16 q-rows)
// per block, 512 threads = 8 waves. q/k/v arrive as bf16: staging is pure
// uint4 copies (K) / ushort scatter (V^T); Q fragments load directly.
// MFMA layouts as k0: A row=lane&15,k=(lane>>4)*8+j; B col=lane&15;
// C/D col=lane&15,row=(lane>>4)*4+reg.
// ---------------------------------------------------------------------------
__global__ __launch_bounds__(512) void k2_attn_proj(
    const unsigned short* __restrict__ qb, const unsigned short* __restrict__ kb,
    const unsigned short* __restrict__ vb, const int* __restrict__ mask,
    const float* __restrict__ Wo, float* __restrict__ pool) {
  __shared__ unsigned short sK[L * WCS];    // K bf16 [64][136]   17.4 KB
  __shared__ unsigned short sVt[D * VTS];   // V^T bf16 [128][72] 18.4 KB
  __shared__ unsigned short woT[D * WCS];   // Wo^T bf16 [128][136] 34.8 KB
  __shared__ float sS[16 * 68];             // scores f32          4.3 KB
  __shared__ unsigned short sP[16 * VTS];   // P bf16 [16][72]     2.3 KB
  __shared__ unsigned short sO[16 * WCS];   // O bf16 [16][136]    4.3 KB
  __shared__ float pmaxArr[D];              //                     0.5 KB
  const int t = threadIdx.x;
  const int wv_ = t >> 6, lane = t & 63;
  const int m = lane & 15;
  const int kg = lane >> 4;
  const int b = blockIdx.x / SPLIT;
  const int sp = blockIdx.x % SPLIT;
  // ---- stage K and V^T (bf16 direct copies) ----
  {
    const unsigned short* kbp = kb + (size_t)(b * L) * D;
    const unsigned short* vbp = vb + (size_t)(b * L) * D;
#pragma unroll
    for (int it = 0; it < 2; ++it) {
      const int i = (t + it * 512) * 8;     // 8 bf16 = 16B per thread
      const int r = i >> 7, c = i & 127;
      uint4 kv = *(const uint4*)&kbp[r * D + c];
      *(uint4*)&sK[r * WCS + c] = kv;
      union { uint4 u4; unsigned short s[8]; } vv;
      vv.u4 = *(const uint4*)&vbp[r * D + c];
#pragma unroll
      for (int j = 0; j < 8; ++j) sVt[(c + j) * VTS + r] = vv.s[j];
    }
  }
  // ---- stage Wo^T (bf16) ----
  for (int i = t; i < D * D / 4; i += 512) {
    const int d = i >> 5;
    const int e0 = (i & 31) * 4;
    float4 wv = *(const float4*)&Wo[d * D + e0];
    woT[(e0 + 0) * WCS + d] = f2bf(wv.x);
    woT[(e0 + 1) * WCS + d] = f2bf(wv.y);
    woT[(e0 + 2) * WCS + d] = f2bf(wv.z);
    woT[(e0 + 3) * WCS + d] = f2bf(wv.w);
  }
  // ---- Q fragments (waves 0-3; q-row = m, direct bf16 loads) ----
  bf16x8 qfrag[4];
  if (wv_ < 4) {
    const unsigned short* qp = qb + (size_t)(b * L + sp * 16 + m) * D;
#pragma unroll
    for (int kc = 0; kc < 4; ++kc)
      qfrag[kc] = *(const bf16x8*)&qp[kc * 32 + kg * 8];
  }
  __syncthreads();
  // ---- S = Q @ K^T (waves 0-3; key-tile = wv_) ----
  if (wv_ < 4) {
    f32x4 acc = {0.f, 0.f, 0.f, 0.f};
#pragma unroll
    for (int kc = 0; kc < 4; ++kc) {
      bf16x8 bfrag = *(const bf16x8*)&sK[(wv_ * 16 + m) * WCS + kc * 32 + kg * 8];
      acc = __builtin_amdgcn_mfma_f32_16x16x32_bf16(qfrag[kc], bfrag, acc, 0, 0, 0);
    }
#pragma unroll
    for (int r = 0; r < 4; ++r)
      sS[(kg * 4 + r) * 68 + wv_ * 16 + m] = acc[r];
  }
  __syncthreads();
  // ---- softmax: 16 rows x 32 threads (2 keys each) ----
  {
    const int row = t >> 5;
    const int k2i = (t & 31) * 2;
    float s0 = sS[row * 68 + k2i] * 0.08838834764831845f;
    float s1 = sS[row * 68 + k2i + 1] * 0.08838834764831845f;
    const int* mp = &mask[((size_t)(b * L + sp * 16 + row)) * L + k2i];
    if (mp[0] <= 0) s0 = -1e9f;
    if (mp[1] <= 0) s1 = -1e9f;
    float mx = fmaxf(s0, s1);
#pragma unroll
    for (int off = 16; off >= 1; off >>= 1) mx = fmaxf(mx, __shfl_xor(mx, off));
    float e0 = __expf(s0 - mx), e1 = __expf(s1 - mx);
    float sm = e0 + e1;
#pragma unroll
    for (int off = 16; off >= 1; off >>= 1) sm += __shfl_xor(sm, off);
    float inv = 1.0f / sm;
    unsigned short p0 = f2bf(e0 * inv), p1 = f2bf(e1 * inv);
    *(unsigned*)&sP[row * VTS + k2i] = (unsigned)p0 | ((unsigned)p1 << 16);
  }
  __syncthreads();
  // ---- O = P @ V (8 waves; dim-tile = wv_) ----
  {
    f32x4 acc = {0.f, 0.f, 0.f, 0.f};
#pragma unroll
    for (int kc = 0; kc < 2; ++kc) {
      bf16x8 pa = *(const bf16x8*)&sP[m * VTS + kc * 32 + kg * 8];
      bf16x8 vf = *(const bf16x8*)&sVt[(wv_ * 16 + m) * VTS + kc * 32 + kg * 8];
      acc = __builtin_amdgcn_mfma_f32_16x16x32_bf16(pa, vf, acc, 0, 0, 0);
    }
#pragma unroll
    for (int r = 0; r < 4; ++r)
      sO[(kg * 4 + r) * WCS + wv_ * 16 + m] = f2bf(acc[r]);
  }
  __syncthreads();
  // ---- OWo + pooled max (8 waves; out-tile = wv_) ----
  {
    f32x4 acc = {0.f, 0.f, 0.f, 0.f};
#pragma unroll
    for (int kc = 0; kc < 4; ++kc) {
      bf16x8 oa = *(const bf16x8*)&sO[m * WCS + kc * 32 + kg * 8];
      bf16x8 wb = *(const bf16x8*)&woT[(wv_ * 16 + m) * WCS + kc * 32 + kg * 8];
      acc = __builtin_amdgcn_mfma_f32_16x16x32_bf16(oa, wb, acc, 0, 0, 0);
    }
    float v = fmaxf(fmaxf(acc[0], acc[1]), fmaxf(acc[2], acc[3]));
    v = fmaxf(v, __shfl_xor(v, 16));
    v = fmaxf(v, __shfl_xor(v, 32));
    if (kg == 0) pmaxArr[wv_ * 16 + m] = v;
  }
  __syncthreads();
  if (t < D) pool[(size_t)blockIdx.x * D + t] = pmaxArr[t];
}

// ---------------------------------------------------------------------------
// K3: final pooled max over splits + logits
// ---------------------------------------------------------------------------
__global__ __launch_bounds__(128) void k3_logits(const float* __restrict__ pool,
                                                 const float* __restrict__ Wl,
                                                 const float* __restrict__ bl,
                                                 float* __restrict__ out) {
  __shared__ float sP2[D];
  const int b = blockIdx.x, t = threadIdx.x;
  float pv = pool[((size_t)b * SPLIT) * D + t];
#pragma unroll
  for (int i = 1; i < SPLIT; ++i)
    pv = fmaxf(pv, pool[((size_t)b * SPLIT + i) * D + t]);
  sP2[t] = pv;
  __syncthreads();
  if (t < LABELS) {
    float a = bl[t];
#pragma unroll 4
    for (int d = 0; d < D; ++d) a += sP2[d] * Wl[d * LABELS + t];
    out[b * LABELS + t] = a;
  }
}

extern "C" void kernel_launch(void* const* d_in, const int* in_sizes, int n_in,
                              void* d_out, int out_size, void* d_ws, size_t ws_size,
                              hipStream_t stream) {
  const int* tokens = (const int*)d_in[0];
  const int* mask = (const int*)d_in[1];
  const float* emb = (const float*)d_in[2];
  const float* Wc = (const float*)d_in[3];
  const float* bc = (const float*)d_in[4];
  const float* Wq = (const float*)d_in[5];
  const float* Wk = (const float*)d_in[6];
  const float* Wv = (const float*)d_in[7];
  const float* Wo = (const float*)d_in[8];
  const float* Wl = (const float*)d_in[9];
  const float* bl = (const float*)d_in[10];
  float* out = (float*)d_out;

  __hip_bfloat16* T = (__hip_bfloat16*)d_ws;            // VOCAB*D bf16 = 7.68 MB
  unsigned short* qb = (unsigned short*)(T + (size_t)VOCAB * D);  // B*L*D bf16 each
  unsigned short* kb = qb + (size_t)B * L * D;
  unsigned short* vb = kb + (size_t)B * L * D;
  float* pool = (float*)(vb + (size_t)B * L * D);       // B*SPLIT*D f32

  hipLaunchKernelGGL(k0_embWc, dim3((VOCAB + 63) / 64), dim3(256), 0, stream,
                     emb, Wc, bc, T);
  hipLaunchKernelGGL(k1_tree_qkv, dim3(B * L / 8), dim3(512), 0, stream,
                     tokens, T, Wq, Wk, Wv, qb, kb, vb);
  hipLaunchKernelGGL(k2_attn_proj, dim3(B * SPLIT), dim3(512), 0, stream,
                     qb, kb, vb, mask, Wo, pool);
  hipLaunchKernelGGL(k3_logits, dim3(B), dim3(128), 0, stream,
                     pool, Wl, bl, out);
}